// Round 2
// baseline (29012.128 us; speedup 1.0000x reference)
//
#include <hip/hip_runtime.h>
#include <math.h>

#define NT 512        // time steps
#define NB 512        // batch
#define HID 128
#define NIN 10
#define NC 10         // memory cells
#define CW 20         // cell width
#define NIF 88        // interface size
#define NOUT 10
#define GB 2          // batches per workgroup
#define BLK 512       // threads per block (8 waves)

typedef _Float16 h1;
typedef _Float16 h2 __attribute__((ext_vector_type(2)));

__device__ __forceinline__ float sigf(float x) { return 1.0f / (1.0f + expf(-x)); }
// jax.nn.softplus == logaddexp(x, 0)
__device__ __forceinline__ float splus(float x) { return fmaxf(x, 0.0f) + log1pf(expf(-fabsf(x))); }

// fp16 x fp16 -> fp32 accumulate (compiler emits v_fma_mix_f32)
__device__ __forceinline__ float mix2(h2 w, h2 h, float acc) {
  acc += (float)w.x * (float)h.x;
  acc += (float)w.y * (float)h.y;
  return acc;
}

// within-wave LDS ordering fence (no workgroup barrier)
#define LDSFENCE() do { asm volatile("s_waitcnt lgkmcnt(0)" ::: "memory"); \
                        __builtin_amdgcn_sched_barrier(0); } while (0)

#define MIX8(WARR, base, fa, fb)                                      \
  a0 = mix2(WARR[(base)+0], __builtin_bit_cast(h2, fa.x), a0);        \
  a1 = mix2(WARR[(base)+0], __builtin_bit_cast(h2, fb.x), a1);        \
  a2 = mix2(WARR[(base)+1], __builtin_bit_cast(h2, fa.y), a2);        \
  a3 = mix2(WARR[(base)+1], __builtin_bit_cast(h2, fb.y), a3);        \
  a0 = mix2(WARR[(base)+2], __builtin_bit_cast(h2, fa.z), a0);        \
  a1 = mix2(WARR[(base)+2], __builtin_bit_cast(h2, fb.z), a1);        \
  a2 = mix2(WARR[(base)+3], __builtin_bit_cast(h2, fa.w), a2);        \
  a3 = mix2(WARR[(base)+3], __builtin_bit_cast(h2, fb.w), a3);

__global__ __launch_bounds__(BLK, 2) void dnc_regws_kernel(
    const float* __restrict__ x,
    const float* __restrict__ Wih0, const float* __restrict__ Whh0, const float* __restrict__ b0,
    const float* __restrict__ Wih1, const float* __restrict__ Whh1, const float* __restrict__ b1,
    const float* __restrict__ Wif,  const float* __restrict__ bif,
    const float* __restrict__ Wout, const float* __restrict__ bout,
    float* __restrict__ out)
{
  // ---- LDS ----
  __shared__ __align__(16) h2   s_wif[NIF * 68];          // [q][k2], row padded to 68 h2 (17 float4)
  __shared__ __align__(16) h1   s_inph[GB][32];           // [x(10), rv(20), pad(2)] fp16
  __shared__ __align__(16) h1   s_h0h[GB][HID];
  __shared__ __align__(16) h1   s_h1h[GB][HID];
  __shared__ __align__(16) h1   s_ctrlh[GB][HID];
  __shared__ __align__(16) float s_g[GB][4*HID];
  __shared__ __align__(16) float s_ctrl[GB][HID];         // fp32 for epilogue
  __shared__ __align__(16) float s_mem[GB][NC][CW];
  __shared__ float s_rk[GB][CW], s_wk[GB][CW], s_er[GB][CW], s_wv[GB][CW];
  __shared__ float s_mraw[GB][3];
  __shared__ float s_sc[GB][8];     // 0:rs 1:ws 2:fg 3:ga 4:gw 5:m0 6:m1 7:m2
  __shared__ float s_usage[GB][NC], s_u[GB][NC];
  __shared__ float s_prec[GB][NC], s_prec2[GB][NC];
  __shared__ float s_link[GB][NC][NC];
  __shared__ float s_rw[GB][NC], s_ww[GB][NC];
  __shared__ float s_rv[GB][CW];
  __shared__ float s_cw[GB][NC], s_cr[GB][NC], s_fwd[GB][NC], s_bwd[GB][NC];

  const int tid = threadIdx.x;
  const int bg  = blockIdx.x * GB;

  // ---- per-thread register-stationary fp16 weights (row r = tid) ----
  h2 wih0[16], whh0[64], wih1[64], whh1[64];
  float b0r, b1r;
  {
    const int r = tid;
    const float* p = Wih0 + (size_t)r * (NIN + CW);
    #pragma unroll
    for (int k = 0; k < 15; ++k) { h2 v; v.x=(h1)p[2*k]; v.y=(h1)p[2*k+1]; wih0[k]=v; }
    { h2 v; v.x=(h1)0.f; v.y=(h1)0.f; wih0[15]=v; }
    const float4* q4 = (const float4*)(Whh0 + (size_t)r*HID);
    #pragma unroll
    for (int k = 0; k < 32; ++k) { float4 f=q4[k]; h2 a,b;
      a.x=(h1)f.x; a.y=(h1)f.y; b.x=(h1)f.z; b.y=(h1)f.w; whh0[2*k]=a; whh0[2*k+1]=b; }
    q4 = (const float4*)(Wih1 + (size_t)r*HID);
    #pragma unroll
    for (int k = 0; k < 32; ++k) { float4 f=q4[k]; h2 a,b;
      a.x=(h1)f.x; a.y=(h1)f.y; b.x=(h1)f.z; b.y=(h1)f.w; wih1[2*k]=a; wih1[2*k+1]=b; }
    q4 = (const float4*)(Whh1 + (size_t)r*HID);
    #pragma unroll
    for (int k = 0; k < 32; ++k) { float4 f=q4[k]; h2 a,b;
      a.x=(h1)f.x; a.y=(h1)f.y; b.x=(h1)f.z; b.y=(h1)f.w; whh1[2*k]=a; whh1[2*k+1]=b; }
    b0r = b0[r]; b1r = b1[r];
  }
  const float bifq = (tid < GB*NIF) ? bif[tid % NIF] : 0.f;

  // ---- Wif -> LDS (fp16, padded rows) ----
  for (int idx = tid; idx < NIF*64; idx += BLK) {
    int qq = idx >> 6, k2 = idx & 63;
    h2 v; v.x = (h1)Wif[qq*HID + 2*k2]; v.y = (h1)Wif[qq*HID + 2*k2 + 1];
    s_wif[qq*68 + k2] = v;
  }

  // ---- zero-init state ----
  for (int i = tid; i < GB*HID; i += BLK) { int b=i>>7, j=i&127;
    s_h0h[b][j]=(h1)0.f; s_h1h[b][j]=(h1)0.f; s_ctrlh[b][j]=(h1)0.f; s_ctrl[b][j]=0.f; }
  for (int i = tid; i < GB*NC*CW; i += BLK) { int b=i/(NC*CW), e=i%(NC*CW);
    s_mem[b][e/CW][e%CW]=0.f; }
  for (int i = tid; i < GB*NC*NC; i += BLK) { int b=i/(NC*NC), e=i%(NC*NC);
    s_link[b][e/NC][e%NC]=0.f; }
  if (tid < GB*NC) { int b=tid/NC, n=tid%NC;
    s_usage[b][n]=0.f; s_prec[b][n]=0.f; s_rw[b][n]=0.f; s_ww[b][n]=0.f; }
  if (tid < GB*CW) { int b=tid/CW, c=tid%CW; s_rv[b][c]=0.f; }
  if (tid < GB*32) { int b=tid>>5, i=tid&31;
    float v = 0.f;
    if (i < NIN) v = x[((size_t)(bg+b)*NT + 0)*NIN + i];
    s_inph[b][i] = (h1)v;
  }
  float c0r = 0.f, c1r = 0.f;   // cell states (threads 0..255: b=tid>>7, j=tid&127)
  __syncthreads();

  for (int t = 0; t < NT; ++t) {
    // ---- B: gates0 = [x,rv] @ Wih0^T + h0_old @ Whh0^T + b0 ----
    {
      float a0=b0r, a1=b0r, a2=0.f, a3=0.f;
      const float4* Ia = (const float4*)s_inph[0];
      const float4* Ib = (const float4*)s_inph[1];
      #pragma unroll
      for (int i = 0; i < 4; ++i) { float4 fa=Ia[i], fb=Ib[i]; MIX8(wih0, 4*i, fa, fb); }
      const float4* Ha = (const float4*)s_h0h[0];
      const float4* Hb = (const float4*)s_h0h[1];
      #pragma unroll
      for (int i = 0; i < 16; ++i) { float4 fa=Ha[i], fb=Hb[i]; MIX8(whh0, 4*i, fa, fb); }
      s_g[0][tid] = a0+a2; s_g[1][tid] = a1+a3;
    }
    __syncthreads();

    // ---- C: LSTM0 nonlinearity ----
    if (tid < GB*HID) {
      int b = tid>>7, j = tid&127;
      float gi=s_g[b][j], gf=s_g[b][HID+j], gg=s_g[b][2*HID+j], go=s_g[b][3*HID+j];
      float c = sigf(gf)*c0r + sigf(gi)*tanhf(gg);
      c0r = c;
      float h = sigf(go)*tanhf(c);
      s_h0h[b][j] = (h1)h;
    }
    __syncthreads();

    // ---- D: gates1 = h0_new @ Wih1^T + h1_old @ Whh1^T + b1 ----
    {
      float a0=b1r, a1=b1r, a2=0.f, a3=0.f;
      const float4* Ha = (const float4*)s_h0h[0];
      const float4* Hb = (const float4*)s_h0h[1];
      #pragma unroll
      for (int i = 0; i < 16; ++i) { float4 fa=Ha[i], fb=Hb[i]; MIX8(wih1, 4*i, fa, fb); }
      const float4* Ga = (const float4*)s_h1h[0];
      const float4* Gb = (const float4*)s_h1h[1];
      #pragma unroll
      for (int i = 0; i < 16; ++i) { float4 fa=Ga[i], fb=Gb[i]; MIX8(whh1, 4*i, fa, fb); }
      s_g[0][tid] = a0+a2; s_g[1][tid] = a1+a3;
    }
    __syncthreads();

    // ---- E: LSTM1 nonlinearity + ctrl clip ----
    if (tid < GB*HID) {
      int b = tid>>7, j = tid&127;
      float gi=s_g[b][j], gf=s_g[b][HID+j], gg=s_g[b][2*HID+j], go=s_g[b][3*HID+j];
      float c = sigf(gf)*c1r + sigf(gi)*tanhf(gg);
      c1r = c;
      float h = sigf(go)*tanhf(c);
      float ctl = fminf(fmaxf(h, -20.f), 20.f);
      s_h1h[b][j] = (h1)h;
      s_ctrl[b][j] = ctl;
      s_ctrlh[b][j] = (h1)ctl;
    }
    __syncthreads();

    // ---- F: xi = ctrl @ Wif^T + bif, fused transforms ----
    if (tid < GB*NIF) {
      int b = tid / NIF, q = tid - b*NIF;
      float a0 = bifq, a2 = 0.f;
      const float4* Wq = ((const float4*)s_wif) + q*17;
      const float4* Cq = (const float4*)s_ctrlh[b];
      #pragma unroll
      for (int i = 0; i < 16; ++i) {
        float4 w = Wq[i], c = Cq[i];
        a0 = mix2(__builtin_bit_cast(h2,w.x), __builtin_bit_cast(h2,c.x), a0);
        a2 = mix2(__builtin_bit_cast(h2,w.y), __builtin_bit_cast(h2,c.y), a2);
        a0 = mix2(__builtin_bit_cast(h2,w.z), __builtin_bit_cast(h2,c.z), a0);
        a2 = mix2(__builtin_bit_cast(h2,w.w), __builtin_bit_cast(h2,c.w), a2);
      }
      float a = a0 + a2;
      if      (q < 20)  s_rk[b][q]    = tanhf(a);
      else if (q == 20) s_sc[b][0]    = splus(a);
      else if (q < 41)  s_wk[b][q-21] = tanhf(a);
      else if (q == 41) s_sc[b][1]    = splus(a);
      else if (q < 62)  s_er[b][q-42] = sigf(a);
      else if (q < 82)  s_wv[b][q-62] = tanhf(a);
      else if (q == 82) s_sc[b][2]    = sigf(a);
      else if (q == 83) s_sc[b][3]    = sigf(a);
      else if (q == 84) s_sc[b][4]    = sigf(a);
      else              s_mraw[b][q-85] = a;
    }
    __syncthreads();

    // ---- W0: all DNC memory ops, wave 0 only, LDS fences instead of barriers ----
    if (tid < 64) {
      const int lane = tid;
      // prefetch next x early (latency hidden under H..L)
      float xv = 0.f;
      if (lane >= GB*CW && lane < GB*CW + GB*NIN && (t+1) < NT) {
        int q = lane - GB*CW, b = q/NIN, i = q%NIN;
        xv = x[((size_t)(bg+b)*NT + (t+1))*NIN + i];
      }

      // H: usage/psi + write-content sims + modes softmax
      if (lane < GB*NC) {
        int b = lane/NC, n = lane%NC;
        float fg = s_sc[b][2];
        float psi = 1.f - fg * s_rw[b][n];
        float u = s_usage[b][n], w = s_ww[b][n];
        u = (u + w - u*w) * psi;
        s_usage[b][n] = u;
        s_u[b][n] = 1e-6f + (1.0f - 1e-6f) * u;
        float dot=0.f, mn=0.f, kn=0.f;
        #pragma unroll
        for (int c = 0; c < CW; ++c) {
          float m = s_mem[b][n][c], k = s_wk[b][c];
          dot += k*m; mn += m*m; kn += k*k;
        }
        s_cw[b][n] = dot / (sqrtf(kn)*sqrtf(mn) + 1e-6f) * s_sc[b][1];
      } else if (lane < GB*NC + GB) {
        int b = lane - GB*NC;
        float m0=s_mraw[b][0], m1=s_mraw[b][1], m2=s_mraw[b][2];
        float mm = fmaxf(m0, fmaxf(m1, m2));
        float e0=expf(m0-mm), e1=expf(m1-mm), e2=expf(m2-mm);
        float es = e0+e1+e2;
        s_sc[b][5]=e0/es; s_sc[b][6]=e1/es; s_sc[b][7]=e2/es;
      }
      LDSFENCE();

      // I: cw softmax + rank-based allocation + new ww
      if (lane < GB*NC) {
        int b = lane/NC, n = lane%NC;
        float vals[NC], uu[NC];
        #pragma unroll
        for (int m = 0; m < NC; ++m) { vals[m]=s_cw[b][m]; uu[m]=s_u[b][m]; }
        float mx = -1e30f;
        #pragma unroll
        for (int m = 0; m < NC; ++m) mx = fmaxf(mx, vals[m]);
        float sm = 0.f;
        #pragma unroll
        for (int m = 0; m < NC; ++m) sm += expf(vals[m]-mx);
        float cw = expf(vals[n]-mx) / sm;
        float un = uu[n];
        float excl = 1.f;
        #pragma unroll
        for (int m = 0; m < NC; ++m) {
          float um = uu[m];
          bool before = (um < un) || (um == un && m < n);
          excl *= before ? um : 1.f;
        }
        float alloc = (1.f - un) * excl;
        float ga = s_sc[b][3], gw = s_sc[b][4];
        s_ww[b][n] = gw * (ga*alloc + (1.f-ga)*cw);
      }
      LDSFENCE();

      // J: memory write + link update (old prec) + prec2
      #pragma unroll
      for (int e = lane; e < GB*NC*CW; e += 64) {
        int b = e/(NC*CW), r = (e%(NC*CW))/CW, c = e%CW;
        float w = s_ww[b][r];
        s_mem[b][r][c] = s_mem[b][r][c] * (1.f - w*s_er[b][c]) + w*s_wv[b][c];
      }
      #pragma unroll
      for (int e = lane; e < GB*NC*NC; e += 64) {
        int b = e/(NC*NC), i = (e%(NC*NC))/NC, j = e%NC;
        float wi = s_ww[b][i], wj = s_ww[b][j];
        float l = (1.f - wi - wj)*s_link[b][i][j] + wi*s_prec[b][j];
        s_link[b][i][j] = (i==j) ? 0.f : l;
      }
      if (lane < GB*NC) {
        int b = lane/NC, n = lane%NC;
        float sw = 0.f;
        #pragma unroll
        for (int m = 0; m < NC; ++m) sw += s_ww[b][m];
        s_prec2[b][n] = (1.f - sw)*s_prec[b][n] + s_ww[b][n];
      }
      LDSFENCE();

      // K: commit prec, fwd/bwd on new link, read-content sims on new mem
      if (lane < GB*NC) {
        int b = lane/NC, m = lane%NC;
        s_prec[b][m] = s_prec2[b][m];
        float a = 0.f;
        #pragma unroll
        for (int n = 0; n < NC; ++n) a += s_rw[b][n]*s_link[b][m][n];
        s_fwd[b][m] = a;
      } else if (lane < 2*GB*NC) {
        int q = lane - GB*NC, b = q/NC, m = q%NC;
        float a = 0.f;
        #pragma unroll
        for (int n = 0; n < NC; ++n) a += s_rw[b][n]*s_link[b][n][m];
        s_bwd[b][m] = a;
      } else if (lane < 3*GB*NC) {
        int q = lane - 2*GB*NC, b = q/NC, n = q%NC;
        float dot=0.f, mn=0.f, kn=0.f;
        #pragma unroll
        for (int c = 0; c < CW; ++c) {
          float m = s_mem[b][n][c], k = s_rk[b][c];
          dot += k*m; mn += m*m; kn += k*k;
        }
        s_cr[b][n] = dot/(sqrtf(kn)*sqrtf(mn)+1e-6f) * s_sc[b][0];
      }
      LDSFENCE();

      // L: cr softmax + new read weights
      if (lane < GB*NC) {
        int b = lane/NC, n = lane%NC;
        float vals[NC];
        #pragma unroll
        for (int m = 0; m < NC; ++m) vals[m] = s_cr[b][m];
        float mx = -1e30f;
        #pragma unroll
        for (int m = 0; m < NC; ++m) mx = fmaxf(mx, vals[m]);
        float sm = 0.f;
        #pragma unroll
        for (int m = 0; m < NC; ++m) sm += expf(vals[m]-mx);
        float cr = expf(vals[n]-mx)/sm;
        s_rw[b][n] = s_sc[b][5]*s_bwd[b][n] + s_sc[b][6]*cr + s_sc[b][7]*s_fwd[b][n];
      }
      LDSFENCE();

      // M: read vectors + pack next-step input (x part from prefetch)
      if (lane < GB*CW) {
        int b = lane/CW, c = lane%CW;
        float a = 0.f;
        #pragma unroll
        for (int n = 0; n < NC; ++n) a += s_rw[b][n]*s_mem[b][n][c];
        s_rv[b][c] = a;
        s_inph[b][NIN + c] = (h1)a;
      } else if (lane < GB*CW + GB*NIN && (t+1) < NT) {
        int q = lane - GB*CW, b = q/NIN, i = q%NIN;
        s_inph[b][i] = (h1)xv;
      }
    }
    __syncthreads();
  }

  // ---- epilogue: y_T = [ctrl, rv] @ Wout^T + bout ----
  if (tid < GB*NOUT) {
    int b = tid/NOUT, o = tid%NOUT;
    float a = bout[o];
    const float* Wr = Wout + o*(HID+CW);
    #pragma unroll 4
    for (int k = 0; k < HID; ++k) a += Wr[k]*s_ctrl[b][k];
    #pragma unroll
    for (int c = 0; c < CW; ++c) a += Wr[HID+c]*s_rv[b][c];
    out[(size_t)(bg+b)*NOUT + o] = a;
  }
}

extern "C" void kernel_launch(void* const* d_in, const int* in_sizes, int n_in,
                              void* d_out, int out_size, void* d_ws, size_t ws_size,
                              hipStream_t stream) {
  (void)in_sizes; (void)n_in; (void)out_size; (void)d_ws; (void)ws_size;
  const float* x    = (const float*)d_in[0];
  const float* Wih0 = (const float*)d_in[1];
  const float* Whh0 = (const float*)d_in[2];
  const float* b0   = (const float*)d_in[3];
  const float* Wih1 = (const float*)d_in[4];
  const float* Whh1 = (const float*)d_in[5];
  const float* b1   = (const float*)d_in[6];
  const float* Wif  = (const float*)d_in[7];
  const float* bif  = (const float*)d_in[8];
  const float* Wout = (const float*)d_in[9];
  const float* bout = (const float*)d_in[10];
  float* out = (float*)d_out;
  dnc_regws_kernel<<<dim3(NB/GB), dim3(BLK), 0, stream>>>(
      x, Wih0, Whh0, b0, Wih1, Whh1, b1, Wif, bif, Wout, bout, out);
}

// Round 3
// 7183.535 us; speedup vs baseline: 4.0387x; 4.0387x over previous
//
#include <hip/hip_runtime.h>
#include <math.h>

#define NT 512        // time steps
#define NB 512        // batch
#define HID 128
#define NIN 10
#define NC 10         // memory cells
#define CW 20         // cell width
#define NIF 88        // interface size
#define NOUT 10
#define GB 2          // batches per workgroup
#define BLK 512       // threads per block (8 waves)

typedef _Float16 h1;
typedef _Float16 h2 __attribute__((ext_vector_type(2)));

__device__ __forceinline__ float sigf(float x) { return 1.0f / (1.0f + expf(-x)); }
// jax.nn.softplus == logaddexp(x, 0)
__device__ __forceinline__ float splus(float x) { return fmaxf(x, 0.0f) + log1pf(expf(-fabsf(x))); }

// fp16 pair dot with fp32 accumulate: v_dot2_f32_f16
__device__ __forceinline__ float dot2(h2 a, h2 b, float c) {
#if __has_builtin(__builtin_amdgcn_fdot2)
  return __builtin_amdgcn_fdot2(a, b, c, false);
#else
  c += (float)a.x * (float)b.x;
  c += (float)a.y * (float)b.y;
  return c;
#endif
}

// within-wave LDS ordering fence (no workgroup barrier)
#define LDSFENCE() do { asm volatile("s_waitcnt lgkmcnt(0)" ::: "memory"); \
                        __builtin_amdgcn_sched_barrier(0); } while (0)

// 4 weight h2 (registers) x one float4 (8 fp16 activations), 2 batches
#define DOTR4(W, base, fa, fb)                                        \
  a0 = dot2(W[(base)+0], __builtin_bit_cast(h2,(fa).x), a0);          \
  a1 = dot2(W[(base)+0], __builtin_bit_cast(h2,(fb).x), a1);          \
  a2 = dot2(W[(base)+1], __builtin_bit_cast(h2,(fa).y), a2);          \
  a3 = dot2(W[(base)+1], __builtin_bit_cast(h2,(fb).y), a3);          \
  a0 = dot2(W[(base)+2], __builtin_bit_cast(h2,(fa).z), a0);          \
  a1 = dot2(W[(base)+2], __builtin_bit_cast(h2,(fb).z), a1);          \
  a2 = dot2(W[(base)+3], __builtin_bit_cast(h2,(fa).w), a2);          \
  a3 = dot2(W[(base)+3], __builtin_bit_cast(h2,(fb).w), a3);

// one float4 of LDS weights (8 fp16) x one float4 of activations, 2 batches
#define DOTL4(w4, fa, fb)                                                                 \
  a0 = dot2(__builtin_bit_cast(h2,(w4).x), __builtin_bit_cast(h2,(fa).x), a0);            \
  a1 = dot2(__builtin_bit_cast(h2,(w4).x), __builtin_bit_cast(h2,(fb).x), a1);            \
  a2 = dot2(__builtin_bit_cast(h2,(w4).y), __builtin_bit_cast(h2,(fa).y), a2);            \
  a3 = dot2(__builtin_bit_cast(h2,(w4).y), __builtin_bit_cast(h2,(fb).y), a3);            \
  a0 = dot2(__builtin_bit_cast(h2,(w4).z), __builtin_bit_cast(h2,(fa).z), a0);            \
  a1 = dot2(__builtin_bit_cast(h2,(w4).z), __builtin_bit_cast(h2,(fb).z), a1);            \
  a2 = dot2(__builtin_bit_cast(h2,(w4).w), __builtin_bit_cast(h2,(fa).w), a2);            \
  a3 = dot2(__builtin_bit_cast(h2,(w4).w), __builtin_bit_cast(h2,(fb).w), a3);

__device__ __forceinline__ float4 pack8(const float* p) {
  h2 v0, v1, v2, v3;
  v0.x=(h1)p[0]; v0.y=(h1)p[1]; v1.x=(h1)p[2]; v1.y=(h1)p[3];
  v2.x=(h1)p[4]; v2.y=(h1)p[5]; v3.x=(h1)p[6]; v3.y=(h1)p[7];
  float4 r;
  r.x=__builtin_bit_cast(float,v0); r.y=__builtin_bit_cast(float,v1);
  r.z=__builtin_bit_cast(float,v2); r.w=__builtin_bit_cast(float,v3);
  return r;
}

__global__ __launch_bounds__(BLK, 1) void dnc_regws_kernel(
    const float* __restrict__ x,
    const float* __restrict__ Wih0, const float* __restrict__ Whh0, const float* __restrict__ b0,
    const float* __restrict__ Wih1, const float* __restrict__ Whh1, const float* __restrict__ b1,
    const float* __restrict__ Wif,  const float* __restrict__ bif,
    const float* __restrict__ Wout, const float* __restrict__ bout,
    float* __restrict__ out)
{
  // ---- LDS ----
  __shared__ __align__(16) float4 s_whh0b[512][4];   // quarter rows (elems 96..127), swizzled
  __shared__ __align__(16) float4 s_wih1b[512][4];
  __shared__ __align__(16) float4 s_whh1b[512][4];
  __shared__ __align__(16) h2   s_wif[NIF * 64];     // [q][k2] fp16, rows broadcast-read
  __shared__ __align__(16) h1   s_inph[GB][32];      // [x(10), rv(20), pad(2)] fp16
  __shared__ __align__(16) h1   s_h0h[GB][HID];
  __shared__ __align__(16) h1   s_h1h[GB][HID];
  __shared__ __align__(16) h1   s_ctrlh[GB][HID];
  __shared__ __align__(16) float s_g[GB][4*HID];
  __shared__ __align__(16) float s_ctrl[GB][HID];    // fp32 for epilogue
  __shared__ __align__(16) float s_mem[GB][NC][CW];
  __shared__ float s_rk[GB][CW], s_wk[GB][CW], s_er[GB][CW], s_wv[GB][CW];
  __shared__ float s_mraw[GB][3];
  __shared__ float s_sc[GB][8];     // 0:rs 1:ws 2:fg 3:ga 4:gw 5:m0 6:m1 7:m2
  __shared__ float s_usage[GB][NC], s_u[GB][NC];
  __shared__ float s_prec[GB][NC], s_prec2[GB][NC];
  __shared__ float s_link[GB][NC][NC];
  __shared__ float s_rw[GB][NC], s_ww[GB][NC];
  __shared__ float s_rv[GB][CW];
  __shared__ float s_cw[GB][NC], s_cr[GB][NC], s_fwd[GB][NC], s_bwd[GB][NC];

  const int tid = threadIdx.x;
  const int bg  = blockIdx.x * GB;
  const int sw  = (tid >> 2) & 3;   // read-side chunk swizzle for this thread's row

  // ---- per-thread register weights: elems 0..95 of each 128-wide row + full Wih0 row ----
  h2 wih0r[16], whh0r[48], wih1r[48], whh1r[48];     // 160 VGPRs of weights
  float b0r, b1r;
  {
    const int r = tid;
    const float* p = Wih0 + (size_t)r * (NIN + CW);
    #pragma unroll
    for (int k = 0; k < 15; ++k) { h2 v; v.x=(h1)p[2*k]; v.y=(h1)p[2*k+1]; wih0r[k]=v; }
    { h2 v; v.x=(h1)0.f; v.y=(h1)0.f; wih0r[15]=v; }
    const float* q = Whh0 + (size_t)r*HID;
    #pragma unroll
    for (int k = 0; k < 48; ++k) { h2 v; v.x=(h1)q[2*k]; v.y=(h1)q[2*k+1]; whh0r[k]=v; }
    q = Wih1 + (size_t)r*HID;
    #pragma unroll
    for (int k = 0; k < 48; ++k) { h2 v; v.x=(h1)q[2*k]; v.y=(h1)q[2*k+1]; wih1r[k]=v; }
    q = Whh1 + (size_t)r*HID;
    #pragma unroll
    for (int k = 0; k < 48; ++k) { h2 v; v.x=(h1)q[2*k]; v.y=(h1)q[2*k+1]; whh1r[k]=v; }
    b0r = b0[r]; b1r = b1[r];
  }
  const float bifq = (tid < GB*NIF) ? bif[tid % NIF] : 0.f;

  // ---- LDS quarter rows (elems 96..127), chunk-swizzled for conflict-free reads ----
  for (int idx = tid; idx < 512*4; idx += BLK) {
    int r = idx >> 2, c = idx & 3;
    int cc = c ^ ((r >> 2) & 3);
    s_whh0b[r][cc] = pack8(Whh0 + (size_t)r*HID + 96 + 8*c);
    s_wih1b[r][cc] = pack8(Wih1 + (size_t)r*HID + 96 + 8*c);
    s_whh1b[r][cc] = pack8(Whh1 + (size_t)r*HID + 96 + 8*c);
  }
  // ---- Wif -> LDS fp16 ----
  for (int idx = tid; idx < NIF*64; idx += BLK) {
    int qq = idx >> 6, k2 = idx & 63;
    h2 v; v.x = (h1)Wif[qq*HID + 2*k2]; v.y = (h1)Wif[qq*HID + 2*k2 + 1];
    s_wif[qq*64 + k2] = v;
  }

  // ---- zero-init state ----
  for (int i = tid; i < GB*HID; i += BLK) { int b=i>>7, j=i&127;
    s_h0h[b][j]=(h1)0.f; s_h1h[b][j]=(h1)0.f; s_ctrlh[b][j]=(h1)0.f; s_ctrl[b][j]=0.f; }
  for (int i = tid; i < GB*NC*CW; i += BLK) { int b=i/(NC*CW), e=i%(NC*CW);
    s_mem[b][e/CW][e%CW]=0.f; }
  for (int i = tid; i < GB*NC*NC; i += BLK) { int b=i/(NC*NC), e=i%(NC*NC);
    s_link[b][e/NC][e%NC]=0.f; }
  if (tid < GB*NC) { int b=tid/NC, n=tid%NC;
    s_usage[b][n]=0.f; s_prec[b][n]=0.f; s_rw[b][n]=0.f; s_ww[b][n]=0.f; }
  if (tid < GB*CW) { int b=tid/CW, c=tid%CW; s_rv[b][c]=0.f; }
  if (tid < GB*32) { int b=tid>>5, i=tid&31;
    float v = 0.f;
    if (i < NIN) v = x[((size_t)(bg+b)*NT + 0)*NIN + i];
    s_inph[b][i] = (h1)v;
  }
  float c0r = 0.f, c1r = 0.f;   // LSTM cell states (threads 0..255: b=tid>>7, j=tid&127)
  __syncthreads();

  for (int t = 0; t < NT; ++t) {
    // ---- B: gates0 = [x,rv] @ Wih0^T + h0_old @ Whh0^T + b0 ----
    {
      float a0=b0r, a1=b0r, a2=0.f, a3=0.f;
      const float4* Ia = (const float4*)s_inph[0];
      const float4* Ib = (const float4*)s_inph[1];
      #pragma unroll
      for (int i = 0; i < 4; ++i) { float4 fa=Ia[i], fb=Ib[i]; DOTR4(wih0r, 4*i, fa, fb); }
      const float4* Ha = (const float4*)s_h0h[0];
      const float4* Hb = (const float4*)s_h0h[1];
      #pragma unroll
      for (int i = 0; i < 12; ++i) { float4 fa=Ha[i], fb=Hb[i]; DOTR4(whh0r, 4*i, fa, fb); }
      #pragma unroll
      for (int c = 0; c < 4; ++c) {
        float4 w4 = s_whh0b[tid][c ^ sw];
        float4 fa = Ha[12+c], fb = Hb[12+c];
        DOTL4(w4, fa, fb);
      }
      s_g[0][tid] = a0+a2; s_g[1][tid] = a1+a3;
    }
    __syncthreads();

    // ---- C: LSTM0 nonlinearity ----
    if (tid < GB*HID) {
      int b = tid>>7, j = tid&127;
      float gi=s_g[b][j], gf=s_g[b][HID+j], gg=s_g[b][2*HID+j], go=s_g[b][3*HID+j];
      float c = sigf(gf)*c0r + sigf(gi)*tanhf(gg);
      c0r = c;
      float h = sigf(go)*tanhf(c);
      s_h0h[b][j] = (h1)h;
    }
    __syncthreads();

    // ---- D: gates1 = h0_new @ Wih1^T + h1_old @ Whh1^T + b1 ----
    {
      float a0=b1r, a1=b1r, a2=0.f, a3=0.f;
      const float4* Ha = (const float4*)s_h0h[0];
      const float4* Hb = (const float4*)s_h0h[1];
      #pragma unroll
      for (int i = 0; i < 12; ++i) { float4 fa=Ha[i], fb=Hb[i]; DOTR4(wih1r, 4*i, fa, fb); }
      #pragma unroll
      for (int c = 0; c < 4; ++c) {
        float4 w4 = s_wih1b[tid][c ^ sw];
        float4 fa = Ha[12+c], fb = Hb[12+c];
        DOTL4(w4, fa, fb);
      }
      const float4* Ga = (const float4*)s_h1h[0];
      const float4* Gb = (const float4*)s_h1h[1];
      #pragma unroll
      for (int i = 0; i < 12; ++i) { float4 fa=Ga[i], fb=Gb[i]; DOTR4(whh1r, 4*i, fa, fb); }
      #pragma unroll
      for (int c = 0; c < 4; ++c) {
        float4 w4 = s_whh1b[tid][c ^ sw];
        float4 fa = Ga[12+c], fb = Gb[12+c];
        DOTL4(w4, fa, fb);
      }
      s_g[0][tid] = a0+a2; s_g[1][tid] = a1+a3;
    }
    __syncthreads();

    // ---- E: LSTM1 nonlinearity + ctrl clip ----
    if (tid < GB*HID) {
      int b = tid>>7, j = tid&127;
      float gi=s_g[b][j], gf=s_g[b][HID+j], gg=s_g[b][2*HID+j], go=s_g[b][3*HID+j];
      float c = sigf(gf)*c1r + sigf(gi)*tanhf(gg);
      c1r = c;
      float h = sigf(go)*tanhf(c);
      float ctl = fminf(fmaxf(h, -20.f), 20.f);
      s_h1h[b][j] = (h1)h;
      s_ctrl[b][j] = ctl;
      s_ctrlh[b][j] = (h1)ctl;
    }
    __syncthreads();

    // ---- F: xi = ctrl @ Wif^T + bif, fused transforms ----
    if (tid < GB*NIF) {
      int b = tid / NIF, q = tid - b*NIF;
      float a0 = bifq, a2 = 0.f;
      const float4* Wq = ((const float4*)s_wif) + q*16;
      const float4* Cq = (const float4*)s_ctrlh[b];
      #pragma unroll
      for (int i = 0; i < 16; ++i) {
        float4 w = Wq[i], c = Cq[i];
        a0 = dot2(__builtin_bit_cast(h2,w.x), __builtin_bit_cast(h2,c.x), a0);
        a2 = dot2(__builtin_bit_cast(h2,w.y), __builtin_bit_cast(h2,c.y), a2);
        a0 = dot2(__builtin_bit_cast(h2,w.z), __builtin_bit_cast(h2,c.z), a0);
        a2 = dot2(__builtin_bit_cast(h2,w.w), __builtin_bit_cast(h2,c.w), a2);
      }
      float a = a0 + a2;
      if      (q < 20)  s_rk[b][q]    = tanhf(a);
      else if (q == 20) s_sc[b][0]    = splus(a);
      else if (q < 41)  s_wk[b][q-21] = tanhf(a);
      else if (q == 41) s_sc[b][1]    = splus(a);
      else if (q < 62)  s_er[b][q-42] = sigf(a);
      else if (q < 82)  s_wv[b][q-62] = tanhf(a);
      else if (q == 82) s_sc[b][2]    = sigf(a);
      else if (q == 83) s_sc[b][3]    = sigf(a);
      else if (q == 84) s_sc[b][4]    = sigf(a);
      else              s_mraw[b][q-85] = a;
    }
    __syncthreads();

    // ---- W0: all DNC memory ops, wave 0 only, LDS fences instead of barriers ----
    if (tid < 64) {
      const int lane = tid;
      // prefetch next x early (latency hidden under H..L)
      float xv = 0.f;
      if (lane >= GB*CW && lane < GB*CW + GB*NIN && (t+1) < NT) {
        int q = lane - GB*CW, b = q/NIN, i = q%NIN;
        xv = x[((size_t)(bg+b)*NT + (t+1))*NIN + i];
      }

      // H: usage/psi + write-content sims + modes softmax
      if (lane < GB*NC) {
        int b = lane/NC, n = lane%NC;
        float fg = s_sc[b][2];
        float psi = 1.f - fg * s_rw[b][n];
        float u = s_usage[b][n], w = s_ww[b][n];
        u = (u + w - u*w) * psi;
        s_usage[b][n] = u;
        s_u[b][n] = 1e-6f + (1.0f - 1e-6f) * u;
        float dot=0.f, mn=0.f, kn=0.f;
        #pragma unroll
        for (int c = 0; c < CW; ++c) {
          float m = s_mem[b][n][c], k = s_wk[b][c];
          dot += k*m; mn += m*m; kn += k*k;
        }
        s_cw[b][n] = dot / (sqrtf(kn)*sqrtf(mn) + 1e-6f) * s_sc[b][1];
      } else if (lane < GB*NC + GB) {
        int b = lane - GB*NC;
        float m0=s_mraw[b][0], m1=s_mraw[b][1], m2=s_mraw[b][2];
        float mm = fmaxf(m0, fmaxf(m1, m2));
        float e0=expf(m0-mm), e1=expf(m1-mm), e2=expf(m2-mm);
        float es = e0+e1+e2;
        s_sc[b][5]=e0/es; s_sc[b][6]=e1/es; s_sc[b][7]=e2/es;
      }
      LDSFENCE();

      // I: cw softmax + rank-based allocation + new ww
      if (lane < GB*NC) {
        int b = lane/NC, n = lane%NC;
        float mx = -1e30f;
        #pragma unroll
        for (int m = 0; m < NC; ++m) mx = fmaxf(mx, s_cw[b][m]);
        float sm = 0.f;
        #pragma unroll
        for (int m = 0; m < NC; ++m) sm += expf(s_cw[b][m]-mx);
        float cwv = expf(s_cw[b][n]-mx) / sm;
        float un = s_u[b][n];
        float excl = 1.f;
        #pragma unroll
        for (int m = 0; m < NC; ++m) {
          float um = s_u[b][m];
          bool before = (um < un) || (um == un && m < n);
          excl *= before ? um : 1.f;
        }
        float alloc = (1.f - un) * excl;
        float ga = s_sc[b][3], gw = s_sc[b][4];
        s_ww[b][n] = gw * (ga*alloc + (1.f-ga)*cwv);
      }
      LDSFENCE();

      // J: memory write + link update (old prec) + prec2
      #pragma unroll
      for (int e = lane; e < GB*NC*CW; e += 64) {
        int b = e/(NC*CW), r = (e%(NC*CW))/CW, c = e%CW;
        float w = s_ww[b][r];
        s_mem[b][r][c] = s_mem[b][r][c] * (1.f - w*s_er[b][c]) + w*s_wv[b][c];
      }
      #pragma unroll
      for (int e = lane; e < GB*NC*NC; e += 64) {
        int b = e/(NC*NC), i = (e%(NC*NC))/NC, j = e%NC;
        float wi = s_ww[b][i], wj = s_ww[b][j];
        float l = (1.f - wi - wj)*s_link[b][i][j] + wi*s_prec[b][j];
        s_link[b][i][j] = (i==j) ? 0.f : l;
      }
      if (lane < GB*NC) {
        int b = lane/NC, n = lane%NC;
        float sw2 = 0.f;
        #pragma unroll
        for (int m = 0; m < NC; ++m) sw2 += s_ww[b][m];
        s_prec2[b][n] = (1.f - sw2)*s_prec[b][n] + s_ww[b][n];
      }
      LDSFENCE();

      // K: commit prec, fwd/bwd on new link, read-content sims on new mem
      if (lane < GB*NC) {
        int b = lane/NC, m = lane%NC;
        s_prec[b][m] = s_prec2[b][m];
        float a = 0.f;
        #pragma unroll
        for (int n = 0; n < NC; ++n) a += s_rw[b][n]*s_link[b][m][n];
        s_fwd[b][m] = a;
      } else if (lane < 2*GB*NC) {
        int q = lane - GB*NC, b = q/NC, m = q%NC;
        float a = 0.f;
        #pragma unroll
        for (int n = 0; n < NC; ++n) a += s_rw[b][n]*s_link[b][n][m];
        s_bwd[b][m] = a;
      } else if (lane < 3*GB*NC) {
        int q = lane - 2*GB*NC, b = q/NC, n = q%NC;
        float dot=0.f, mn=0.f, kn=0.f;
        #pragma unroll
        for (int c = 0; c < CW; ++c) {
          float m = s_mem[b][n][c], k = s_rk[b][c];
          dot += k*m; mn += m*m; kn += k*k;
        }
        s_cr[b][n] = dot/(sqrtf(kn)*sqrtf(mn)+1e-6f) * s_sc[b][0];
      }
      LDSFENCE();

      // L: cr softmax + new read weights
      if (lane < GB*NC) {
        int b = lane/NC, n = lane%NC;
        float mx = -1e30f;
        #pragma unroll
        for (int m = 0; m < NC; ++m) mx = fmaxf(mx, s_cr[b][m]);
        float sm = 0.f;
        #pragma unroll
        for (int m = 0; m < NC; ++m) sm += expf(s_cr[b][m]-mx);
        float cr = expf(s_cr[b][n]-mx)/sm;
        s_rw[b][n] = s_sc[b][5]*s_bwd[b][n] + s_sc[b][6]*cr + s_sc[b][7]*s_fwd[b][n];
      }
      LDSFENCE();

      // M: read vectors + pack next-step input (x part from prefetch)
      if (lane < GB*CW) {
        int b = lane/CW, c = lane%CW;
        float a = 0.f;
        #pragma unroll
        for (int n = 0; n < NC; ++n) a += s_rw[b][n]*s_mem[b][n][c];
        s_rv[b][c] = a;
        s_inph[b][NIN + c] = (h1)a;
      } else if (lane < GB*CW + GB*NIN && (t+1) < NT) {
        int q = lane - GB*CW, b = q/NIN, i = q%NIN;
        s_inph[b][i] = (h1)xv;
      }
    }
    __syncthreads();
  }

  // ---- epilogue: y_T = [ctrl, rv] @ Wout^T + bout ----
  if (tid < GB*NOUT) {
    int b = tid/NOUT, o = tid%NOUT;
    float a = bout[o];
    const float* Wr = Wout + o*(HID+CW);
    #pragma unroll 4
    for (int k = 0; k < HID; ++k) a += Wr[k]*s_ctrl[b][k];
    #pragma unroll
    for (int c = 0; c < CW; ++c) a += Wr[HID+c]*s_rv[b][c];
    out[(size_t)(bg+b)*NOUT + o] = a;
  }
}

extern "C" void kernel_launch(void* const* d_in, const int* in_sizes, int n_in,
                              void* d_out, int out_size, void* d_ws, size_t ws_size,
                              hipStream_t stream) {
  (void)in_sizes; (void)n_in; (void)out_size; (void)d_ws; (void)ws_size;
  const float* x    = (const float*)d_in[0];
  const float* Wih0 = (const float*)d_in[1];
  const float* Whh0 = (const float*)d_in[2];
  const float* b0   = (const float*)d_in[3];
  const float* Wih1 = (const float*)d_in[4];
  const float* Whh1 = (const float*)d_in[5];
  const float* b1   = (const float*)d_in[6];
  const float* Wif  = (const float*)d_in[7];
  const float* bif  = (const float*)d_in[8];
  const float* Wout = (const float*)d_in[9];
  const float* bout = (const float*)d_in[10];
  float* out = (float*)d_out;
  dnc_regws_kernel<<<dim3(NB/GB), dim3(BLK), 0, stream>>>(
      x, Wih0, Whh0, b0, Wih1, Whh1, b1, Wif, bif, Wout, bout, out);
}

// Round 4
// 7164.987 us; speedup vs baseline: 4.0492x; 1.0026x over previous
//
#include <hip/hip_runtime.h>
#include <math.h>

#define NT 512        // time steps
#define NB 512        // batch
#define HID 128
#define NIN 10
#define NC 10         // memory cells
#define CW 20         // cell width
#define NIF 88        // interface size
#define NOUT 10
#define GB 2          // batches per workgroup
#define BLK 512       // threads per block (8 waves)

typedef _Float16 h1;
typedef _Float16 h2 __attribute__((ext_vector_type(2)));

__device__ __forceinline__ float sigf(float x) { return 1.0f / (1.0f + expf(-x)); }
// jax.nn.softplus == logaddexp(x, 0)
__device__ __forceinline__ float splus(float x) { return fmaxf(x, 0.0f) + log1pf(expf(-fabsf(x))); }

// fp16 pair dot with fp32 accumulate: v_dot2_f32_f16
__device__ __forceinline__ float dot2(h2 a, h2 b, float c) {
#if __has_builtin(__builtin_amdgcn_fdot2)
  return __builtin_amdgcn_fdot2(a, b, c, false);
#else
  c += (float)a.x * (float)b.x;
  c += (float)a.y * (float)b.y;
  return c;
#endif
}

// within-wave LDS ordering fence (no workgroup barrier)
#define LDSFENCE() do { asm volatile("s_waitcnt lgkmcnt(0)" ::: "memory"); \
                        __builtin_amdgcn_sched_barrier(0); } while (0)

#define BC(f) __builtin_bit_cast(h2, f)

// one float4 of packed fp16 weights (8 elems) x 8 fp16 activations, 2 batches
#define DOTF4(W, fa, fb)                                   \
  a0 = dot2(BC((W).x), BC((fa).x), a0);                    \
  a1 = dot2(BC((W).x), BC((fb).x), a1);                    \
  a2 = dot2(BC((W).y), BC((fa).y), a2);                    \
  a3 = dot2(BC((W).y), BC((fb).y), a3);                    \
  a0 = dot2(BC((W).z), BC((fa).z), a0);                    \
  a1 = dot2(BC((W).z), BC((fb).z), a1);                    \
  a2 = dot2(BC((W).w), BC((fa).w), a2);                    \
  a3 = dot2(BC((W).w), BC((fb).w), a3);

#define LSTEP(W, i, Pa, Pb) { float4 fa = (Pa)[i], fb = (Pb)[i]; DOTF4(W, fa, fb) }

__device__ __forceinline__ float4 pack8(const float* p) {
  h2 v0, v1, v2, v3;
  v0.x=(h1)p[0]; v0.y=(h1)p[1]; v1.x=(h1)p[2]; v1.y=(h1)p[3];
  v2.x=(h1)p[4]; v2.y=(h1)p[5]; v3.x=(h1)p[6]; v3.y=(h1)p[7];
  float4 r;
  r.x=__builtin_bit_cast(float,v0); r.y=__builtin_bit_cast(float,v1);
  r.z=__builtin_bit_cast(float,v2); r.w=__builtin_bit_cast(float,v3);
  return r;
}
__device__ __forceinline__ float4 pack6z(const float* p) {
  h2 v0, v1, v2, v3;
  v0.x=(h1)p[0]; v0.y=(h1)p[1]; v1.x=(h1)p[2]; v1.y=(h1)p[3];
  v2.x=(h1)p[4]; v2.y=(h1)p[5]; v3.x=(h1)0.f;  v3.y=(h1)0.f;
  float4 r;
  r.x=__builtin_bit_cast(float,v0); r.y=__builtin_bit_cast(float,v1);
  r.z=__builtin_bit_cast(float,v2); r.w=__builtin_bit_cast(float,v3);
  return r;
}

__global__ __launch_bounds__(BLK) __attribute__((amdgpu_waves_per_eu(2, 2)))
void dnc_regws_kernel(
    const float* __restrict__ x,
    const float* __restrict__ Wih0, const float* __restrict__ Whh0, const float* __restrict__ b0,
    const float* __restrict__ Wih1, const float* __restrict__ Whh1, const float* __restrict__ b1,
    const float* __restrict__ Wif,  const float* __restrict__ bif,
    const float* __restrict__ Wout, const float* __restrict__ bout,
    float* __restrict__ out)
{
  // ---- LDS ----
  __shared__ __align__(16) float4 s_q[3][4][512];    // [mat][chunk][row]: row-elems 96+8c..103+8c, lane-contiguous
  __shared__ __align__(16) h1   s_inph[GB][32];      // [x(10), rv(20), pad(2)] fp16
  __shared__ __align__(16) h1   s_h0h[GB][HID];
  __shared__ __align__(16) h1   s_h1h[GB][HID];
  __shared__ __align__(16) h1   s_ctrlh[GB][HID];
  __shared__ __align__(16) float s_g[GB][4*HID];
  __shared__ __align__(16) float s_ctrl[GB][HID];    // fp32 for epilogue
  __shared__ __align__(16) float s_mem[GB][NC][CW];
  __shared__ float s_fp[NIF*9];                       // interface partials, stride-9 padded
  __shared__ float s_rk[GB][CW], s_wk[GB][CW], s_er[GB][CW], s_wv[GB][CW];
  __shared__ float s_mraw[GB][3];
  __shared__ float s_sc[GB][8];     // 0:rs 1:ws 2:fg 3:ga 4:gw 5:m0 6:m1 7:m2
  __shared__ float s_usage[GB][NC], s_u[GB][NC];
  __shared__ float s_prec[GB][NC], s_prec2[GB][NC];
  __shared__ float s_link[GB][NC][NC];
  __shared__ float s_rw[GB][NC], s_ww[GB][NC];
  __shared__ float s_rv[GB][CW];
  __shared__ float s_cw[GB][NC], s_cr[GB][NC], s_fwd[GB][NC], s_bwd[GB][NC];

  const int tid = threadIdx.x;
  const int bg  = blockIdx.x * GB;

  // ---- named-SSA register weights (no arrays -> no promote-alloca scratch) ----
  // A: Wih0 row tid (30 elems + 2 pad). B/C/D: elems 0..95 of Whh0/Wih1/Whh1 row tid.
  // E: Wif quarter-row (tid<352: q=tid>>2, quarter=tid&3).
  float4 A0,A1,A2,A3;
  float4 B0,B1,B2,B3,B4,B5,B6,B7,B8,B9,B10,B11;
  float4 C0,C1,C2,C3,C4,C5,C6,C7,C8,C9,C10,C11;
  float4 D0,D1,D2,D3,D4,D5,D6,D7,D8,D9,D10,D11;
  float4 E0,E1,E2,E3;
  float b0r, b1r;
  {
    const int r = tid;
    const float* p = Wih0 + (size_t)r * (NIN + CW);
    A0=pack8(p); A1=pack8(p+8); A2=pack8(p+16); A3=pack6z(p+24);
    const float* q0 = Whh0 + (size_t)r*HID;
    B0=pack8(q0);    B1=pack8(q0+8);  B2=pack8(q0+16); B3=pack8(q0+24);
    B4=pack8(q0+32); B5=pack8(q0+40); B6=pack8(q0+48); B7=pack8(q0+56);
    B8=pack8(q0+64); B9=pack8(q0+72); B10=pack8(q0+80); B11=pack8(q0+88);
    const float* q1 = Wih1 + (size_t)r*HID;
    C0=pack8(q1);    C1=pack8(q1+8);  C2=pack8(q1+16); C3=pack8(q1+24);
    C4=pack8(q1+32); C5=pack8(q1+40); C6=pack8(q1+48); C7=pack8(q1+56);
    C8=pack8(q1+64); C9=pack8(q1+72); C10=pack8(q1+80); C11=pack8(q1+88);
    const float* q2 = Whh1 + (size_t)r*HID;
    D0=pack8(q2);    D1=pack8(q2+8);  D2=pack8(q2+16); D3=pack8(q2+24);
    D4=pack8(q2+32); D5=pack8(q2+40); D6=pack8(q2+48); D7=pack8(q2+56);
    D8=pack8(q2+64); D9=pack8(q2+72); D10=pack8(q2+80); D11=pack8(q2+88);
    b0r = b0[r]; b1r = b1[r];
  }
  if (tid < 4*NIF) {
    const float* e = Wif + (size_t)(tid>>2)*HID + (tid&3)*32;
    E0=pack8(e); E1=pack8(e+8); E2=pack8(e+16); E3=pack8(e+24);
  } else { E0=E1=E2=E3=float4{0.f,0.f,0.f,0.f}; }
  const float bifq = (tid < 2*NIF) ? bif[tid>>1] : 0.f;

  // ---- LDS quarter rows (elems 96..127), transposed [mat][chunk][row] ----
  for (int idx = tid; idx < 4*512; idx += BLK) {
    int c = idx >> 9, rr = idx & 511;
    s_q[0][c][rr] = pack8(Whh0 + (size_t)rr*HID + 96 + 8*c);
    s_q[1][c][rr] = pack8(Wih1 + (size_t)rr*HID + 96 + 8*c);
    s_q[2][c][rr] = pack8(Whh1 + (size_t)rr*HID + 96 + 8*c);
  }

  // ---- zero-init state ----
  for (int i = tid; i < GB*HID; i += BLK) { int b=i>>7, j=i&127;
    s_h0h[b][j]=(h1)0.f; s_h1h[b][j]=(h1)0.f; s_ctrlh[b][j]=(h1)0.f; s_ctrl[b][j]=0.f; }
  for (int i = tid; i < GB*NC*CW; i += BLK) { int b=i/(NC*CW), e=i%(NC*CW);
    s_mem[b][e/CW][e%CW]=0.f; }
  for (int i = tid; i < GB*NC*NC; i += BLK) { int b=i/(NC*NC), e=i%(NC*NC);
    s_link[b][e/NC][e%NC]=0.f; }
  if (tid < GB*NC) { int b=tid/NC, n=tid%NC;
    s_usage[b][n]=0.f; s_prec[b][n]=0.f; s_rw[b][n]=0.f; s_ww[b][n]=0.f; }
  if (tid < GB*CW) { int b=tid/CW, c=tid%CW; s_rv[b][c]=0.f; }
  if (tid < GB*32) { int b=tid>>5, i=tid&31;
    float v = 0.f;
    if (i < NIN) v = x[((size_t)(bg+b)*NT + 0)*NIN + i];
    s_inph[b][i] = (h1)v;
  }
  float c0r = 0.f, c1r = 0.f;   // LSTM cell states (threads 0..255: b=tid>>7, j=tid&127)
  __syncthreads();

  for (int t = 0; t < NT; ++t) {
    // ---- B: gates0 = [x,rv] @ Wih0^T + h0_old @ Whh0^T + b0 ----
    {
      float a0=b0r, a1=b0r, a2=0.f, a3=0.f;
      const float4* Ia = (const float4*)s_inph[0];
      const float4* Ib = (const float4*)s_inph[1];
      LSTEP(A0,0,Ia,Ib) LSTEP(A1,1,Ia,Ib) LSTEP(A2,2,Ia,Ib) LSTEP(A3,3,Ia,Ib)
      const float4* Ha = (const float4*)s_h0h[0];
      const float4* Hb = (const float4*)s_h0h[1];
      LSTEP(B0,0,Ha,Hb)  LSTEP(B1,1,Ha,Hb)  LSTEP(B2,2,Ha,Hb)   LSTEP(B3,3,Ha,Hb)
      LSTEP(B4,4,Ha,Hb)  LSTEP(B5,5,Ha,Hb)  LSTEP(B6,6,Ha,Hb)   LSTEP(B7,7,Ha,Hb)
      LSTEP(B8,8,Ha,Hb)  LSTEP(B9,9,Ha,Hb)  LSTEP(B10,10,Ha,Hb) LSTEP(B11,11,Ha,Hb)
      { float4 w=s_q[0][0][tid]; LSTEP(w,12,Ha,Hb) }
      { float4 w=s_q[0][1][tid]; LSTEP(w,13,Ha,Hb) }
      { float4 w=s_q[0][2][tid]; LSTEP(w,14,Ha,Hb) }
      { float4 w=s_q[0][3][tid]; LSTEP(w,15,Ha,Hb) }
      s_g[0][tid] = a0+a2; s_g[1][tid] = a1+a3;
    }
    __syncthreads();

    // ---- C: LSTM0 nonlinearity ----
    if (tid < GB*HID) {
      int b = tid>>7, j = tid&127;
      float gi=s_g[b][j], gf=s_g[b][HID+j], gg=s_g[b][2*HID+j], go=s_g[b][3*HID+j];
      float c = sigf(gf)*c0r + sigf(gi)*tanhf(gg);
      c0r = c;
      float h = sigf(go)*tanhf(c);
      s_h0h[b][j] = (h1)h;
    }
    __syncthreads();

    // ---- D: gates1 = h0_new @ Wih1^T + h1_old @ Whh1^T + b1 ----
    {
      float a0=b1r, a1=b1r, a2=0.f, a3=0.f;
      const float4* Ha = (const float4*)s_h0h[0];
      const float4* Hb = (const float4*)s_h0h[1];
      LSTEP(C0,0,Ha,Hb)  LSTEP(C1,1,Ha,Hb)  LSTEP(C2,2,Ha,Hb)   LSTEP(C3,3,Ha,Hb)
      LSTEP(C4,4,Ha,Hb)  LSTEP(C5,5,Ha,Hb)  LSTEP(C6,6,Ha,Hb)   LSTEP(C7,7,Ha,Hb)
      LSTEP(C8,8,Ha,Hb)  LSTEP(C9,9,Ha,Hb)  LSTEP(C10,10,Ha,Hb) LSTEP(C11,11,Ha,Hb)
      { float4 w=s_q[1][0][tid]; LSTEP(w,12,Ha,Hb) }
      { float4 w=s_q[1][1][tid]; LSTEP(w,13,Ha,Hb) }
      { float4 w=s_q[1][2][tid]; LSTEP(w,14,Ha,Hb) }
      { float4 w=s_q[1][3][tid]; LSTEP(w,15,Ha,Hb) }
      const float4* Ga = (const float4*)s_h1h[0];
      const float4* Gb = (const float4*)s_h1h[1];
      LSTEP(D0,0,Ga,Gb)  LSTEP(D1,1,Ga,Gb)  LSTEP(D2,2,Ga,Gb)   LSTEP(D3,3,Ga,Gb)
      LSTEP(D4,4,Ga,Gb)  LSTEP(D5,5,Ga,Gb)  LSTEP(D6,6,Ga,Gb)   LSTEP(D7,7,Ga,Gb)
      LSTEP(D8,8,Ga,Gb)  LSTEP(D9,9,Ga,Gb)  LSTEP(D10,10,Ga,Gb) LSTEP(D11,11,Ga,Gb)
      { float4 w=s_q[2][0][tid]; LSTEP(w,12,Ga,Gb) }
      { float4 w=s_q[2][1][tid]; LSTEP(w,13,Ga,Gb) }
      { float4 w=s_q[2][2][tid]; LSTEP(w,14,Ga,Gb) }
      { float4 w=s_q[2][3][tid]; LSTEP(w,15,Ga,Gb) }
      s_g[0][tid] = a0+a2; s_g[1][tid] = a1+a3;
    }
    __syncthreads();

    // ---- E: LSTM1 nonlinearity + ctrl clip ----
    if (tid < GB*HID) {
      int b = tid>>7, j = tid&127;
      float gi=s_g[b][j], gf=s_g[b][HID+j], gg=s_g[b][2*HID+j], go=s_g[b][3*HID+j];
      float c = sigf(gf)*c1r + sigf(gi)*tanhf(gg);
      c1r = c;
      float h = sigf(go)*tanhf(c);
      float ctl = fminf(fmaxf(h, -20.f), 20.f);
      s_h1h[b][j] = (h1)h;
      s_ctrl[b][j] = ctl;
      s_ctrlh[b][j] = (h1)ctl;
    }
    __syncthreads();

    // ---- F-partial: xi partials, 4 threads per interface row (register weights) ----
    if (tid < 4*NIF) {
      int c4 = tid & 3, qq = tid >> 2;
      float a0=0.f, a1=0.f, a2=0.f, a3=0.f;
      const float4* Ca = (const float4*)s_ctrlh[0];
      const float4* Cb = (const float4*)s_ctrlh[1];
      LSTEP(E0, 4*c4+0, Ca, Cb) LSTEP(E1, 4*c4+1, Ca, Cb)
      LSTEP(E2, 4*c4+2, Ca, Cb) LSTEP(E3, 4*c4+3, Ca, Cb)
      s_fp[qq*9 + c4*2 + 0] = a0+a2;
      s_fp[qq*9 + c4*2 + 1] = a1+a3;
    }
    __syncthreads();

    // ---- F-combine: xi = bif + sum partials, fused transforms ----
    if (tid < 2*NIF) {
      int b = tid & 1, q = tid >> 1;
      float a = bifq + s_fp[q*9+b] + s_fp[q*9+2+b] + s_fp[q*9+4+b] + s_fp[q*9+6+b];
      if      (q < 20)  s_rk[b][q]    = tanhf(a);
      else if (q == 20) s_sc[b][0]    = splus(a);
      else if (q < 41)  s_wk[b][q-21] = tanhf(a);
      else if (q == 41) s_sc[b][1]    = splus(a);
      else if (q < 62)  s_er[b][q-42] = sigf(a);
      else if (q < 82)  s_wv[b][q-62] = tanhf(a);
      else if (q == 82) s_sc[b][2]    = sigf(a);
      else if (q == 83) s_sc[b][3]    = sigf(a);
      else if (q == 84) s_sc[b][4]    = sigf(a);
      else              s_mraw[b][q-85] = a;
    }
    __syncthreads();

    // ---- W0: all DNC memory ops, wave 0 only, LDS fences instead of barriers ----
    if (tid < 64) {
      const int lane = tid;
      // prefetch next x early (latency hidden under H..L)
      float xv = 0.f;
      if (lane >= GB*CW && lane < GB*CW + GB*NIN && (t+1) < NT) {
        int q = lane - GB*CW, b = q/NIN, i = q%NIN;
        xv = x[((size_t)(bg+b)*NT + (t+1))*NIN + i];
      }

      // H: usage/psi + write-content sims + modes softmax
      if (lane < GB*NC) {
        int b = lane/NC, n = lane%NC;
        float fg = s_sc[b][2];
        float psi = 1.f - fg * s_rw[b][n];
        float u = s_usage[b][n], w = s_ww[b][n];
        u = (u + w - u*w) * psi;
        s_usage[b][n] = u;
        s_u[b][n] = 1e-6f + (1.0f - 1e-6f) * u;
        float dot=0.f, mn=0.f, kn=0.f;
        #pragma unroll
        for (int c = 0; c < CW; ++c) {
          float m = s_mem[b][n][c], k = s_wk[b][c];
          dot += k*m; mn += m*m; kn += k*k;
        }
        s_cw[b][n] = dot / (sqrtf(kn)*sqrtf(mn) + 1e-6f) * s_sc[b][1];
      } else if (lane < GB*NC + GB) {
        int b = lane - GB*NC;
        float m0=s_mraw[b][0], m1=s_mraw[b][1], m2=s_mraw[b][2];
        float mm = fmaxf(m0, fmaxf(m1, m2));
        float e0=expf(m0-mm), e1=expf(m1-mm), e2=expf(m2-mm);
        float es = e0+e1+e2;
        s_sc[b][5]=e0/es; s_sc[b][6]=e1/es; s_sc[b][7]=e2/es;
      }
      LDSFENCE();

      // I: cw softmax + rank-based allocation + new ww
      if (lane < GB*NC) {
        int b = lane/NC, n = lane%NC;
        float mx = -1e30f;
        #pragma unroll
        for (int m = 0; m < NC; ++m) mx = fmaxf(mx, s_cw[b][m]);
        float sm = 0.f;
        #pragma unroll
        for (int m = 0; m < NC; ++m) sm += expf(s_cw[b][m]-mx);
        float cwv = expf(s_cw[b][n]-mx) / sm;
        float un = s_u[b][n];
        float excl = 1.f;
        #pragma unroll
        for (int m = 0; m < NC; ++m) {
          float um = s_u[b][m];
          bool before = (um < un) || (um == un && m < n);
          excl *= before ? um : 1.f;
        }
        float alloc = (1.f - un) * excl;
        float ga = s_sc[b][3], gw = s_sc[b][4];
        s_ww[b][n] = gw * (ga*alloc + (1.f-ga)*cwv);
      }
      LDSFENCE();

      // J: memory write + link update (old prec) + prec2
      #pragma unroll
      for (int e = lane; e < GB*NC*CW; e += 64) {
        int b = e/(NC*CW), r = (e%(NC*CW))/CW, c = e%CW;
        float w = s_ww[b][r];
        s_mem[b][r][c] = s_mem[b][r][c] * (1.f - w*s_er[b][c]) + w*s_wv[b][c];
      }
      #pragma unroll
      for (int e = lane; e < GB*NC*NC; e += 64) {
        int b = e/(NC*NC), i = (e%(NC*NC))/NC, j = e%NC;
        float wi = s_ww[b][i], wj = s_ww[b][j];
        float l = (1.f - wi - wj)*s_link[b][i][j] + wi*s_prec[b][j];
        s_link[b][i][j] = (i==j) ? 0.f : l;
      }
      if (lane < GB*NC) {
        int b = lane/NC, n = lane%NC;
        float sw2 = 0.f;
        #pragma unroll
        for (int m = 0; m < NC; ++m) sw2 += s_ww[b][m];
        s_prec2[b][n] = (1.f - sw2)*s_prec[b][n] + s_ww[b][n];
      }
      LDSFENCE();

      // K: commit prec, fwd/bwd on new link, read-content sims on new mem
      if (lane < GB*NC) {
        int b = lane/NC, m = lane%NC;
        s_prec[b][m] = s_prec2[b][m];
        float a = 0.f;
        #pragma unroll
        for (int n = 0; n < NC; ++n) a += s_rw[b][n]*s_link[b][m][n];
        s_fwd[b][m] = a;
      } else if (lane < 2*GB*NC) {
        int q = lane - GB*NC, b = q/NC, m = q%NC;
        float a = 0.f;
        #pragma unroll
        for (int n = 0; n < NC; ++n) a += s_rw[b][n]*s_link[b][n][m];
        s_bwd[b][m] = a;
      } else if (lane < 3*GB*NC) {
        int q = lane - 2*GB*NC, b = q/NC, n = q%NC;
        float dot=0.f, mn=0.f, kn=0.f;
        #pragma unroll
        for (int c = 0; c < CW; ++c) {
          float m = s_mem[b][n][c], k = s_rk[b][c];
          dot += k*m; mn += m*m; kn += k*k;
        }
        s_cr[b][n] = dot/(sqrtf(kn)*sqrtf(mn)+1e-6f) * s_sc[b][0];
      }
      LDSFENCE();

      // L: cr softmax + new read weights
      if (lane < GB*NC) {
        int b = lane/NC, n = lane%NC;
        float mx = -1e30f;
        #pragma unroll
        for (int m = 0; m < NC; ++m) mx = fmaxf(mx, s_cr[b][m]);
        float sm = 0.f;
        #pragma unroll
        for (int m = 0; m < NC; ++m) sm += expf(s_cr[b][m]-mx);
        float cr = expf(s_cr[b][n]-mx)/sm;
        s_rw[b][n] = s_sc[b][5]*s_bwd[b][n] + s_sc[b][6]*cr + s_sc[b][7]*s_fwd[b][n];
      }
      LDSFENCE();

      // M: read vectors + pack next-step input (x part from prefetch)
      if (lane < GB*CW) {
        int b = lane/CW, c = lane%CW;
        float a = 0.f;
        #pragma unroll
        for (int n = 0; n < NC; ++n) a += s_rw[b][n]*s_mem[b][n][c];
        s_rv[b][c] = a;
        s_inph[b][NIN + c] = (h1)a;
      } else if (lane < GB*CW + GB*NIN && (t+1) < NT) {
        int q = lane - GB*CW, b = q/NIN, i = q%NIN;
        s_inph[b][i] = (h1)xv;
      }
    }
    __syncthreads();
  }

  // ---- epilogue: y_T = [ctrl, rv] @ Wout^T + bout ----
  if (tid < GB*NOUT) {
    int b = tid/NOUT, o = tid%NOUT;
    float a = bout[o];
    const float* Wr = Wout + o*(HID+CW);
    #pragma unroll 4
    for (int k = 0; k < HID; ++k) a += Wr[k]*s_ctrl[b][k];
    #pragma unroll
    for (int c = 0; c < CW; ++c) a += Wr[HID+c]*s_rv[b][c];
    out[(size_t)(bg+b)*NOUT + o] = a;
  }
}

extern "C" void kernel_launch(void* const* d_in, const int* in_sizes, int n_in,
                              void* d_out, int out_size, void* d_ws, size_t ws_size,
                              hipStream_t stream) {
  (void)in_sizes; (void)n_in; (void)out_size; (void)d_ws; (void)ws_size;
  const float* x    = (const float*)d_in[0];
  const float* Wih0 = (const float*)d_in[1];
  const float* Whh0 = (const float*)d_in[2];
  const float* b0   = (const float*)d_in[3];
  const float* Wih1 = (const float*)d_in[4];
  const float* Whh1 = (const float*)d_in[5];
  const float* b1   = (const float*)d_in[6];
  const float* Wif  = (const float*)d_in[7];
  const float* bif  = (const float*)d_in[8];
  const float* Wout = (const float*)d_in[9];
  const float* bout = (const float*)d_in[10];
  float* out = (float*)d_out;
  dnc_regws_kernel<<<dim3(NB/GB), dim3(BLK), 0, stream>>>(
      x, Wih0, Whh0, b0, Wih1, Whh1, b1, Wif, bif, Wout, bout, out);
}